// Round 11
// baseline (477.406 us; speedup 1.0000x reference)
//
#include <hip/hip_runtime.h>
#include <hip/hip_bf16.h>
#include <hip/hip_fp16.h>
#include <math.h>

// ---------------------------------------------------------------------------
// ActivityRecognitionGCN: 3x GCNConv(+ReLU) -> mean pool per graph -> MLP head
// N=100000 nodes, E=3.2M edges, G=1024 graphs, F: 128->64->64->32
// R10 -> R11: feature-halved gather working set.
//  * All h buffers stored split [2][N][F/2] (halves contiguous). Each agg
//    kernel walks its edges twice, once per half, 4 lanes/node x 8 feats
//    (16B gathers, same instruction count). Active array / phase = 6.4MB
//    (F=64) or 3.2MB (F=32, fits one XCD L2) -> fewer capacity misses.
//    FETCH predicted 170 -> ~115MB per agg_gemm.
//  * Producers write split layout with true-feature indexing; numerics
//    unchanged. Everything else identical to R10 (337 -> 335.7us baseline).
// ---------------------------------------------------------------------------

constexpr int BSHIFT = 8;         // bucket = dst >> 8 (256 nodes per bucket)
constexpr int BMASK  = 255;
constexpr int BCAP   = 10240;     // bucket capacity (mean 8192, +22 sigma)
constexpr int EPB    = 4096;      // edges per partition block

// Per-block LDS counting sort by bucket; coalesced segment write + run map.
__global__ __launch_bounds__(512) void partition_kernel(const int* __restrict__ src,
    const int* __restrict__ dst, int* __restrict__ bucket_cnt,
    unsigned* __restrict__ part, unsigned* __restrict__ runmap,
    int E, int nbuckets, int nblk) {
  __shared__ int lcnt[512];
  __shared__ int lscan[512];
  __shared__ int lcur[512];
  __shared__ unsigned spay[EPB];
  const int t = threadIdx.x;
  const int blk = blockIdx.x;
  const int base = blk * EPB;
  const int lim = min(EPB, E - base);
  int s[8], d[8];
#pragma unroll
  for (int j = 0; j < 8; ++j) {
    int idx = base + j * 512 + t;
    if (idx < E) { s[j] = src[idx]; d[j] = dst[idx]; } else d[j] = -1;
  }
  lcnt[t] = 0;
  __syncthreads();
#pragma unroll
  for (int j = 0; j < 8; ++j)
    if (d[j] >= 0) atomicAdd(&lcnt[d[j] >> BSHIFT], 1);
  __syncthreads();
  const int myv = lcnt[t];
  lscan[t] = myv;
  __syncthreads();
  for (int dd = 1; dd < 512; dd <<= 1) {
    int v = 0;
    if (t >= dd) v = lscan[t - dd];
    __syncthreads();
    if (t >= dd) lscan[t] += v;
    __syncthreads();
  }
  const int excl = lscan[t] - myv;
  if (t < nbuckets) {
    runmap[(size_t)t * nblk + blk] = (unsigned)excl | ((unsigned)myv << 16);
    if (myv > 0) atomicAdd(&bucket_cnt[t], myv);
  }
  lcur[t] = excl;
  __syncthreads();
#pragma unroll
  for (int j = 0; j < 8; ++j) {
    if (d[j] >= 0) {
      int b = d[j] >> BSHIFT;
      int pos = atomicAdd(&lcur[b], 1);
      spay[pos] = ((unsigned)(d[j] & BMASK) << 17) | (unsigned)s[j];
    }
  }
  __syncthreads();
#pragma unroll
  for (int j = 0; j < 8; ++j) {
    int i = j * 512 + t;
    if (i < lim) part[base + i] = spay[i];
  }
}

// Exclusive scan of bucket_cnt (nb <= 512) in a single block.
__global__ __launch_bounds__(256) void scan_buckets_kernel(const int* __restrict__ cnt,
    int* __restrict__ base, int nb) {
  __shared__ int sh[512];
  const int t = threadIdx.x;
  sh[t] = (t < nb) ? cnt[t] : 0;
  sh[t + 256] = (t + 256 < nb) ? cnt[t + 256] : 0;
  __syncthreads();
  for (int d = 1; d < 512; d <<= 1) {
    int v0 = 0, v1 = 0;
    if (t >= d) v0 = sh[t - d];
    if (t + 256 >= d) v1 = sh[t + 256 - d];
    __syncthreads();
    if (t >= d) sh[t] += v0;
    if (t + 256 >= d) sh[t + 256] += v1;
    __syncthreads();
  }
  if (t < nb) base[t] = (t == 0) ? 0 : sh[t - 1];
  if (t + 256 < nb) base[t + 256] = sh[t + 255];
}

// One block (512 thr) per bucket, SINGLE pass over scattered runs:
// stage runs -> LDS ebuf, then degree hist, scan (offs/dinv), and placement
// (direct stores into the bucket's 32KB csr window; single-XCD L2-local).
__global__ __launch_bounds__(512) void fill_bucket_kernel(
    const unsigned* __restrict__ part, const unsigned* __restrict__ runmap,
    const int* __restrict__ bucket_cnt, const int* __restrict__ bucket_base,
    int* __restrict__ offs, float* __restrict__ dinv, int* __restrict__ csr,
    int N, int E, int nblk) {
  __shared__ unsigned ebuf[BCAP];
  __shared__ int rsh[1024];
  __shared__ int ldeg[256];
  __shared__ int lscan[512];
  const int b = blockIdx.x;
  const int t = threadIdx.x;
  const int nb0 = b << BSHIFT;
  const int nn = min(1 << BSHIFT, N - nb0);
  const int wbase = bucket_base[b];
  const int cnt = min(bucket_cnt[b], BCAP);
  const unsigned r0 = (t < nblk) ? runmap[(size_t)b * nblk + t] : 0u;
  const unsigned r1 = (t + 512 < nblk) ? runmap[(size_t)b * nblk + t + 512] : 0u;
  const int c0 = (int)(r0 >> 16), c1 = (int)(r1 >> 16);
  rsh[t] = c0; rsh[t + 512] = c1;
  if (t < 256) ldeg[t] = 0;
  __syncthreads();
  for (int dd = 1; dd < 1024; dd <<= 1) {
    int x0 = 0, x1 = 0;
    if (t >= dd) x0 = rsh[t - dd];
    x1 = rsh[t + 512 - dd];
    __syncthreads();
    if (t >= dd) rsh[t] += x0;
    rsh[t + 512] += x1;
    __syncthreads();
  }
  {  // stage runs into ebuf (the ONLY scattered-read pass)
    int rb = rsh[t] - c0;
    if (c0 > 0) {
      const unsigned* p = part + (size_t)t * EPB + (r0 & 0xFFFFu);
      for (int k = 0; k < c0; ++k) { int o = rb + k; if (o < BCAP) ebuf[o] = p[k]; }
    }
    int rb1 = rsh[t + 512] - c1;
    if (c1 > 0) {
      const unsigned* p = part + (size_t)(t + 512) * EPB + (r1 & 0xFFFFu);
      for (int k = 0; k < c1; ++k) { int o = rb1 + k; if (o < BCAP) ebuf[o] = p[k]; }
    }
  }
  __syncthreads();
  for (int i = t; i < cnt; i += 512) atomicAdd(&ldeg[ebuf[i] >> 17], 1);
  __syncthreads();
  const int myv = (t < 256) ? ldeg[t] : 0;
  lscan[t] = myv;
  __syncthreads();
  for (int d = 1; d < 256; d <<= 1) {
    int v = 0;
    if (t >= d && t < 256) v = lscan[t - d];
    __syncthreads();
    if (t >= d && t < 256) lscan[t] += v;
    __syncthreads();
  }
  const int excl = lscan[t] - myv;
  if (t < nn) {
    offs[nb0 + t] = wbase + excl;
    dinv[nb0 + t] = rsqrtf((float)(myv + 1));
  }
  if (t == 0 && nb0 + nn == N) offs[N] = E;
  if (t < 256) ldeg[t] = excl;  // becomes local cursor
  __syncthreads();
  for (int i = t; i < cnt; i += 512) {
    unsigned v = ebuf[i];
    int pos = atomicAdd(&ldeg[v >> 17], 1);
    if (pos < BCAP) csr[wbase + pos] = (int)(v & 0x1FFFF);
  }
}

// ---------------------------------------------------------------------------
// Dense GEMM (layer 1): Y split [2][n][32] fp16 = X[N,128] @ W1[128,64].
// ---------------------------------------------------------------------------
template <int K, int M>
__global__ __launch_bounds__(256) void gemm_kernel(const float* __restrict__ X,
    const float* __restrict__ W, __half* __restrict__ Y, int n) {
  constexpr int RPB = 32;
  constexpr int XST = K + 4;
  constexpr int MC = M / 16;
  constexpr int HF = M / 2;
  __shared__ __align__(16) float Ws[K * M];
  __shared__ __align__(16) float Xs[RPB * XST];
  const int tid = threadIdx.x;
  const int row0 = blockIdx.x * RPB;
  for (int i = tid * 4; i < K * M; i += 1024)
    *reinterpret_cast<float4*>(&Ws[i]) = *reinterpret_cast<const float4*>(&W[i]);
  for (int i = tid * 4; i < RPB * K; i += 1024) {
    int r = i / K, k = i - r * K;
    int gr = row0 + r;
    float4 v = make_float4(0.f, 0.f, 0.f, 0.f);
    if (gr < n) v = *reinterpret_cast<const float4*>(&X[(size_t)gr * K + k]);
    *reinterpret_cast<float4*>(&Xs[r * XST + k]) = v;
  }
  __syncthreads();
  const int rt = tid & 15;
  const int c = tid >> 4;
  float acc[2][MC];
#pragma unroll
  for (int rr = 0; rr < 2; ++rr)
#pragma unroll
    for (int j = 0; j < MC; ++j) acc[rr][j] = 0.f;
  for (int k4 = 0; k4 < K; k4 += 4) {
    float4 xv[2];
#pragma unroll
    for (int rr = 0; rr < 2; ++rr)
      xv[rr] = *reinterpret_cast<const float4*>(&Xs[(rt + 16 * rr) * XST + k4]);
    const float* xf0 = reinterpret_cast<const float*>(&xv[0]);
    const float* xf1 = reinterpret_cast<const float*>(&xv[1]);
#pragma unroll
    for (int kk = 0; kk < 4; ++kk) {
      float w[MC];
#pragma unroll
      for (int j = 0; j < MC; ++j) w[j] = Ws[(k4 + kk) * M + c * MC + j];
      float x0 = xf0[kk], x1 = xf1[kk];
#pragma unroll
      for (int j = 0; j < MC; ++j) {
        acc[0][j] += x0 * w[j];
        acc[1][j] += x1 * w[j];
      }
    }
  }
  const int c0 = c * MC;             // 0,4,...,60 (stays within one half)
  const int oh = c0 / HF, oc = c0 - oh * HF;
#pragma unroll
  for (int rr = 0; rr < 2; ++rr) {
    int gr = row0 + rt + 16 * rr;
    if (gr < n) {
      union { __half hh[MC]; uint2 u2; } cv;
#pragma unroll
      for (int j = 0; j < MC; ++j) cv.hh[j] = __float2half(acc[rr][j]);
      *reinterpret_cast<uint2*>(Y + (size_t)oh * n * HF + (size_t)gr * HF + oc) = cv.u2;
    }
  }
}

// ---------------------------------------------------------------------------
// Fused GCN layer, split-gather: h is [2][n][32]; block = 64 nodes, 4 lanes
// per node own 8 feats (16B gathers); two half-phases (barrier between) ->
// chip-wide active gather array is one 6.4MB half. Then bias/relu -> LDS ->
// GEMM with W -> y split [2][n][FOUT/2] fp16.
// ---------------------------------------------------------------------------
__device__ inline void h8_acc(uint4 r, float w, float* acc) {
  const __half2* hp = reinterpret_cast<const __half2*>(&r);
#pragma unroll
  for (int q = 0; q < 4; ++q) {
    float2 f = __half22float2(hp[q]);
    acc[2 * q]     += w * f.x;
    acc[2 * q + 1] += w * f.y;
  }
}

template <int FOUT>
__global__ __launch_bounds__(256) void agg_gemm_kernel(
    const __half* __restrict__ h, const int* __restrict__ offs,
    const int* __restrict__ csr, const float* __restrict__ dinv,
    const float* __restrict__ bias, const float* __restrict__ W,
    __half* __restrict__ y, int n) {
  constexpr int FIN = 64;
  constexpr int XST = FIN + 4;
  __shared__ float Xs[64 * XST];                       // 17.4KB
  __shared__ __align__(16) float Wls[FIN * FOUT];
  const int t = threadIdx.x;
  for (int i = t * 4; i < FIN * FOUT; i += 1024)
    *reinterpret_cast<float4*>(&Wls[i]) = *reinterpret_cast<const float4*>(&W[i]);
  const int r = t >> 2;              // local node 0..63
  const int node = blockIdx.x * 64 + r;
  const int fl = (t & 3) * 8;        // feat offset within a 32-half
  int e0 = 0, e1 = 0;
  float di = 0.f;
  if (node < n) { e0 = offs[node]; e1 = offs[node + 1]; di = dinv[node]; }
  const size_t HS = (size_t)n * 32;  // half stride (fp16 elements)
#pragma unroll
  for (int half = 0; half < 2; ++half) {
    const __half* hh = h + (size_t)half * HS + fl;
    float acc[8];
#pragma unroll
    for (int j = 0; j < 8; ++j) acc[j] = 0.f;
    if (node < n) {
      {
        uint4 rr = *reinterpret_cast<const uint4*>(hh + (size_t)node * 32);
        h8_acc(rr, di * di, acc);
      }
      int e = e0;
      for (; e + 4 <= e1; e += 4) {
        int sidx[4];
        float wv[4];
        uint4 rv[4];
#pragma unroll
        for (int u = 0; u < 4; ++u) sidx[u] = csr[e + u];
#pragma unroll
        for (int u = 0; u < 4; ++u) wv[u] = di * dinv[sidx[u]];
#pragma unroll
        for (int u = 0; u < 4; ++u)
          rv[u] = *reinterpret_cast<const uint4*>(hh + (size_t)sidx[u] * 32);
#pragma unroll
        for (int u = 0; u < 4; ++u) h8_acc(rv[u], wv[u], acc);
      }
      for (; e < e1; ++e) {
        int s = csr[e];
        uint4 rr = *reinterpret_cast<const uint4*>(hh + (size_t)s * 32);
        h8_acc(rr, di * dinv[s], acc);
      }
      const int fb = half * 32 + fl;  // true feature base
#pragma unroll
      for (int j = 0; j < 8; ++j)
        Xs[r * XST + fb + j] = fmaxf(acc[j] + bias[fb + j], 0.f);
    }
    __syncthreads();  // phase-align the block (and free Xs hazard for epilogue)
  }
  // GEMM: 4 threads per node, CPT cols each
  constexpr int CPT = FOUT / 4;
  constexpr int HF = FOUT / 2;
  const int c0 = (t & 3) * CPT;
  float o[CPT];
#pragma unroll
  for (int j = 0; j < CPT; ++j) o[j] = 0.f;
  for (int k = 0; k < FIN; ++k) {
    const float xv = Xs[r * XST + k];
#pragma unroll
    for (int j4 = 0; j4 < CPT; j4 += 4) {
      float4 wv = *reinterpret_cast<const float4*>(&Wls[k * FOUT + c0 + j4]);
      o[j4] += xv * wv.x; o[j4 + 1] += xv * wv.y;
      o[j4 + 2] += xv * wv.z; o[j4 + 3] += xv * wv.w;
    }
  }
  if (node < n) {
    const int oh = c0 / HF, oc = c0 - oh * HF;
    union { __half hh[CPT]; uint4 u4[CPT / 8]; } cv;
#pragma unroll
    for (int j = 0; j < CPT; ++j) cv.hh[j] = __float2half(o[j]);
    uint4* dst4 = reinterpret_cast<uint4*>(y + (size_t)oh * n * HF +
                                           (size_t)node * HF + oc);
#pragma unroll
    for (int j = 0; j < CPT / 8; ++j) dst4[j] = cv.u4[j];
  }
}

// ---------------------------------------------------------------------------
// Layer-3 aggregate, split-gather (h = [2][n][16], halves 3.2MB: L2-fit)
// + bias/relu + hierarchical pool. Block = 128 nodes, 2 lanes/node.
// ---------------------------------------------------------------------------
__global__ __launch_bounds__(256) void agg_pool_kernel(const __half* __restrict__ h,
    const int* __restrict__ offs, const int* __restrict__ csr,
    const float* __restrict__ dinv, const float* __restrict__ bias,
    const int* __restrict__ batch, float* __restrict__ gsum, int n, int G) {
  constexpr int GCAP = 8;
  __shared__ float lg[GCAP * 32];
  const int t = threadIdx.x;
  const int node0 = blockIdx.x * 128;
  const int r = t >> 1;              // local node 0..127
  const int node = node0 + r;
  const int fl = (t & 1) * 8;        // feat offset within a 16-half
  for (int i = t; i < GCAP * 32; i += 256) lg[i] = 0.f;
  __syncthreads();
  const int g0 = batch[node0 < n ? node0 : (n - 1)];
  int e0 = 0, e1 = 0, g = -1, rel = 0;
  float di = 0.f;
  if (node < n) {
    e0 = offs[node]; e1 = offs[node + 1]; di = dinv[node];
    g = batch[node]; rel = g - g0;
  }
  const size_t HS = (size_t)n * 16;
#pragma unroll
  for (int half = 0; half < 2; ++half) {
    const __half* hh = h + (size_t)half * HS + fl;
    float acc[8];
#pragma unroll
    for (int j = 0; j < 8; ++j) acc[j] = 0.f;
    if (node < n) {
      {
        uint4 rr = *reinterpret_cast<const uint4*>(hh + (size_t)node * 16);
        h8_acc(rr, di * di, acc);
      }
      int e = e0;
      for (; e + 4 <= e1; e += 4) {
        int sidx[4];
        float wv[4];
        uint4 rv[4];
#pragma unroll
        for (int u = 0; u < 4; ++u) sidx[u] = csr[e + u];
#pragma unroll
        for (int u = 0; u < 4; ++u) wv[u] = di * dinv[sidx[u]];
#pragma unroll
        for (int u = 0; u < 4; ++u)
          rv[u] = *reinterpret_cast<const uint4*>(hh + (size_t)sidx[u] * 16);
#pragma unroll
        for (int u = 0; u < 4; ++u) h8_acc(rv[u], wv[u], acc);
      }
      for (; e < e1; ++e) {
        int s = csr[e];
        uint4 rr = *reinterpret_cast<const uint4*>(hh + (size_t)s * 16);
        h8_acc(rr, di * dinv[s], acc);
      }
      const int fb = half * 16 + fl;  // true feature base
      if (rel < GCAP) {
#pragma unroll
        for (int j = 0; j < 8; ++j)
          atomicAdd(&lg[rel * 32 + fb + j], fmaxf(acc[j] + bias[fb + j], 0.f));
      } else {  // pathological span: direct (rare)
#pragma unroll
        for (int j = 0; j < 8; ++j)
          atomicAdd(&gsum[(size_t)g * 32 + fb + j],
                    fmaxf(acc[j] + bias[fb + j], 0.f));
      }
    }
    __syncthreads();  // phase-align
  }
  for (int i = t; i < GCAP * 32; i += 256) {
    float v = lg[i];
    int gi = g0 * 32 + i;
    if (v != 0.f && gi < G * 32) atomicAdd(&gsum[gi], v);
  }
}

// One thread per graph: range via binary search, mean, MLP, log_softmax.
__global__ __launch_bounds__(256) void head_kernel(const float* __restrict__ gsum,
    const int* __restrict__ batch, const float* __restrict__ Wc1,
    const float* __restrict__ bc1, const float* __restrict__ Wc2,
    const float* __restrict__ bc2, float* __restrict__ out, int n, int G) {
  int g = blockIdx.x * blockDim.x + threadIdx.x;
  if (g >= G) return;
  int lo = 0, hi = n;
  while (lo < hi) { int m = (lo + hi) >> 1; if (batch[m] < g) lo = m + 1; else hi = m; }
  const int s0 = lo;
  lo = s0; hi = n;
  while (lo < hi) { int m = (lo + hi) >> 1; if (batch[m] < g + 1) lo = m + 1; else hi = m; }
  const float inv = 1.0f / fmaxf((float)(lo - s0), 1.0f);
  float p[32];
#pragma unroll
  for (int k = 0; k < 32; ++k) p[k] = gsum[g * 32 + k] * inv;
  float z[16];
#pragma unroll
  for (int j = 0; j < 16; ++j) {
    float a = bc1[j];
#pragma unroll
    for (int k = 0; k < 32; ++k) a += p[k] * Wc1[k * 16 + j];
    z[j] = fmaxf(a, 0.f);
  }
  float lg[16];
  float m = -1e30f;
#pragma unroll
  for (int j = 0; j < 16; ++j) {
    float a = bc2[j];
#pragma unroll
    for (int k = 0; k < 16; ++k) a += z[k] * Wc2[k * 16 + j];
    lg[j] = a;
    m = fmaxf(m, a);
  }
  float ssum = 0.f;
#pragma unroll
  for (int j = 0; j < 16; ++j) ssum += expf(lg[j] - m);
  float lse = logf(ssum);
#pragma unroll
  for (int j = 0; j < 16; ++j) out[g * 16 + j] = lg[j] - m - lse;
}

extern "C" void kernel_launch(void* const* d_in, const int* in_sizes, int n_in,
                              void* d_out, int out_size, void* d_ws, size_t ws_size,
                              hipStream_t stream) {
  const float* x   = (const float*)d_in[0];
  const int*   ei  = (const int*)d_in[1];
  const int*   batch = (const int*)d_in[2];
  const float* W1 = (const float*)d_in[3];
  const float* b1 = (const float*)d_in[4];
  const float* W2 = (const float*)d_in[5];
  const float* b2 = (const float*)d_in[6];
  const float* W3 = (const float*)d_in[7];
  const float* b3 = (const float*)d_in[8];
  const float* Wc1 = (const float*)d_in[9];
  const float* bc1 = (const float*)d_in[10];
  const float* Wc2 = (const float*)d_in[11];
  const float* bc2 = (const float*)d_in[12];

  const int N = in_sizes[2];        // 100000
  const int E = in_sizes[1] / 2;    // 3200000
  const int G = out_size / 16;      // 1024
  const int* src = ei;
  const int* dst = ei + E;
  const int nbuckets = (N + ((1 << BSHIFT) - 1)) >> BSHIFT;  // 391
  const int nblk = (E + EPB - 1) / EPB;                      // 782

  char* ws = (char*)d_ws;
  size_t off = 0;
  auto alloc = [&](size_t bytes) -> void* {
    void* p = ws + off;
    off += (bytes + 511) & ~(size_t)511;
    return p;
  };
  int*   offs   = (int*)alloc(((size_t)N + 1) * 4);
  float* dinv   = (float*)alloc((size_t)N * 4);
  int*   bucket_cnt  = (int*)alloc(2048);
  int*   bucket_base = (int*)alloc(2048);
  unsigned* runmap = (unsigned*)alloc((size_t)nbuckets * nblk * 4);  // 1.2MB
  int*   csr    = (int*)alloc((size_t)E * 4);
  __half* hbufA = (__half*)alloc((size_t)N * 64 * 2);   // layer1 out, [2][N][32]
  __half* hbufB = (__half*)alloc((size_t)N * 64 * 2);   // layer2 out, [2][N][32]
  __half* hbufC = (__half*)alloc((size_t)N * 32 * 2);   // layer3 out, [2][N][16]
  float* gsum   = (float*)alloc((size_t)G * 32 * 4);    // pooled sums
  // partition segments (E*4 = 12.8MB) alias hbufA (12.8MB): consumed by
  // fill_bucket before gemm1 writes hbufA.
  unsigned* part = (unsigned*)hbufA;
  (void)ws_size; (void)n_in;

  // --- CSR build (reused by all 3 layers) ---
  hipMemsetAsync(bucket_cnt, 0, (size_t)nbuckets * 4, stream);
  hipMemsetAsync(gsum, 0, (size_t)G * 32 * 4, stream);
  partition_kernel<<<nblk, 512, 0, stream>>>(src, dst, bucket_cnt, part, runmap,
                                             E, nbuckets, nblk);
  scan_buckets_kernel<<<1, 256, 0, stream>>>(bucket_cnt, bucket_base, nbuckets);
  fill_bucket_kernel<<<nbuckets, 512, 0, stream>>>(part, runmap, bucket_cnt,
                                                   bucket_base, offs, dinv, csr,
                                                   N, E, nblk);

  // --- layer 1 GEMM: x[N,128] @ W1 -> hbufA split fp16 ---
  gemm_kernel<128, 64><<<(N + 31) / 32, 256, 0, stream>>>(x, W1, hbufA, N);
  // --- fused layer1-agg + layer2-GEMM: hbufA -> hbufB ---
  agg_gemm_kernel<64><<<(N + 63) / 64, 256, 0, stream>>>(hbufA, offs, csr, dinv,
                                                         b1, W2, hbufB, N);
  // --- fused layer2-agg + layer3-GEMM: hbufB -> hbufC ---
  agg_gemm_kernel<32><<<(N + 63) / 64, 256, 0, stream>>>(hbufB, offs, csr, dinv,
                                                         b2, W3, hbufC, N);
  // --- layer3-agg + hierarchical pool ---
  agg_pool_kernel<<<(N + 127) / 128, 256, 0, stream>>>(hbufC, offs, csr, dinv,
                                                       b3, batch, gsum, N, G);
  // --- head: mean + MLP + log_softmax ---
  head_kernel<<<(G + 255) / 256, 256, 0, stream>>>(gsum, batch, Wc1, bc1,
                                                   Wc2, bc2, (float*)d_out, N, G);
}

// Round 12
// 474.141 us; speedup vs baseline: 1.0069x; 1.0069x over previous
//
#include <hip/hip_runtime.h>
#include <hip/hip_bf16.h>
#include <hip/hip_fp16.h>
#include <math.h>

// ---------------------------------------------------------------------------
// ActivityRecognitionGCN: 3x GCNConv(+ReLU) -> mean pool per graph -> MLP head
// N=100000 nodes, E=3.2M edges, G=1024 graphs, F: 128->64->64->32
// R10 -> R11: feature-halved gather working set.
//  * All h buffers stored split [2][N][F/2] (halves contiguous). Each agg
//    kernel walks its edges twice, once per half, 4 lanes/node x 8 feats
//    (16B gathers, same instruction count). Active array / phase = 6.4MB
//    (F=64) or 3.2MB (F=32, fits one XCD L2) -> fewer capacity misses.
//    FETCH predicted 170 -> ~115MB per agg_gemm.
//  * Producers write split layout with true-feature indexing; numerics
//    unchanged. Everything else identical to R10 (337 -> 335.7us baseline).
// ---------------------------------------------------------------------------

constexpr int BSHIFT = 8;         // bucket = dst >> 8 (256 nodes per bucket)
constexpr int BMASK  = 255;
constexpr int BCAP   = 10240;     // bucket capacity (mean 8192, +22 sigma)
constexpr int EPB    = 4096;      // edges per partition block

// Per-block LDS counting sort by bucket; coalesced segment write + run map.
__global__ __launch_bounds__(512) void partition_kernel(const int* __restrict__ src,
    const int* __restrict__ dst, int* __restrict__ bucket_cnt,
    unsigned* __restrict__ part, unsigned* __restrict__ runmap,
    int E, int nbuckets, int nblk) {
  __shared__ int lcnt[512];
  __shared__ int lscan[512];
  __shared__ int lcur[512];
  __shared__ unsigned spay[EPB];
  const int t = threadIdx.x;
  const int blk = blockIdx.x;
  const int base = blk * EPB;
  const int lim = min(EPB, E - base);
  int s[8], d[8];
#pragma unroll
  for (int j = 0; j < 8; ++j) {
    int idx = base + j * 512 + t;
    if (idx < E) { s[j] = src[idx]; d[j] = dst[idx]; } else d[j] = -1;
  }
  lcnt[t] = 0;
  __syncthreads();
#pragma unroll
  for (int j = 0; j < 8; ++j)
    if (d[j] >= 0) atomicAdd(&lcnt[d[j] >> BSHIFT], 1);
  __syncthreads();
  const int myv = lcnt[t];
  lscan[t] = myv;
  __syncthreads();
  for (int dd = 1; dd < 512; dd <<= 1) {
    int v = 0;
    if (t >= dd) v = lscan[t - dd];
    __syncthreads();
    if (t >= dd) lscan[t] += v;
    __syncthreads();
  }
  const int excl = lscan[t] - myv;
  if (t < nbuckets) {
    runmap[(size_t)t * nblk + blk] = (unsigned)excl | ((unsigned)myv << 16);
    if (myv > 0) atomicAdd(&bucket_cnt[t], myv);
  }
  lcur[t] = excl;
  __syncthreads();
#pragma unroll
  for (int j = 0; j < 8; ++j) {
    if (d[j] >= 0) {
      int b = d[j] >> BSHIFT;
      int pos = atomicAdd(&lcur[b], 1);
      spay[pos] = ((unsigned)(d[j] & BMASK) << 17) | (unsigned)s[j];
    }
  }
  __syncthreads();
#pragma unroll
  for (int j = 0; j < 8; ++j) {
    int i = j * 512 + t;
    if (i < lim) part[base + i] = spay[i];
  }
}

// Exclusive scan of bucket_cnt (nb <= 512) in a single block.
__global__ __launch_bounds__(256) void scan_buckets_kernel(const int* __restrict__ cnt,
    int* __restrict__ base, int nb) {
  __shared__ int sh[512];
  const int t = threadIdx.x;
  sh[t] = (t < nb) ? cnt[t] : 0;
  sh[t + 256] = (t + 256 < nb) ? cnt[t + 256] : 0;
  __syncthreads();
  for (int d = 1; d < 512; d <<= 1) {
    int v0 = 0, v1 = 0;
    if (t >= d) v0 = sh[t - d];
    if (t + 256 >= d) v1 = sh[t + 256 - d];
    __syncthreads();
    if (t >= d) sh[t] += v0;
    if (t + 256 >= d) sh[t + 256] += v1;
    __syncthreads();
  }
  if (t < nb) base[t] = (t == 0) ? 0 : sh[t - 1];
  if (t + 256 < nb) base[t + 256] = sh[t + 255];
}

// One block (512 thr) per bucket, SINGLE pass over scattered runs:
// stage runs -> LDS ebuf, then degree hist, scan (offs/dinv), and placement
// (direct stores into the bucket's 32KB csr window; single-XCD L2-local).
__global__ __launch_bounds__(512) void fill_bucket_kernel(
    const unsigned* __restrict__ part, const unsigned* __restrict__ runmap,
    const int* __restrict__ bucket_cnt, const int* __restrict__ bucket_base,
    int* __restrict__ offs, float* __restrict__ dinv, int* __restrict__ csr,
    int N, int E, int nblk) {
  __shared__ unsigned ebuf[BCAP];
  __shared__ int rsh[1024];
  __shared__ int ldeg[256];
  __shared__ int lscan[512];
  const int b = blockIdx.x;
  const int t = threadIdx.x;
  const int nb0 = b << BSHIFT;
  const int nn = min(1 << BSHIFT, N - nb0);
  const int wbase = bucket_base[b];
  const int cnt = min(bucket_cnt[b], BCAP);
  const unsigned r0 = (t < nblk) ? runmap[(size_t)b * nblk + t] : 0u;
  const unsigned r1 = (t + 512 < nblk) ? runmap[(size_t)b * nblk + t + 512] : 0u;
  const int c0 = (int)(r0 >> 16), c1 = (int)(r1 >> 16);
  rsh[t] = c0; rsh[t + 512] = c1;
  if (t < 256) ldeg[t] = 0;
  __syncthreads();
  for (int dd = 1; dd < 1024; dd <<= 1) {
    int x0 = 0, x1 = 0;
    if (t >= dd) x0 = rsh[t - dd];
    x1 = rsh[t + 512 - dd];
    __syncthreads();
    if (t >= dd) rsh[t] += x0;
    rsh[t + 512] += x1;
    __syncthreads();
  }
  {  // stage runs into ebuf (the ONLY scattered-read pass)
    int rb = rsh[t] - c0;
    if (c0 > 0) {
      const unsigned* p = part + (size_t)t * EPB + (r0 & 0xFFFFu);
      for (int k = 0; k < c0; ++k) { int o = rb + k; if (o < BCAP) ebuf[o] = p[k]; }
    }
    int rb1 = rsh[t + 512] - c1;
    if (c1 > 0) {
      const unsigned* p = part + (size_t)(t + 512) * EPB + (r1 & 0xFFFFu);
      for (int k = 0; k < c1; ++k) { int o = rb1 + k; if (o < BCAP) ebuf[o] = p[k]; }
    }
  }
  __syncthreads();
  for (int i = t; i < cnt; i += 512) atomicAdd(&ldeg[ebuf[i] >> 17], 1);
  __syncthreads();
  const int myv = (t < 256) ? ldeg[t] : 0;
  lscan[t] = myv;
  __syncthreads();
  for (int d = 1; d < 256; d <<= 1) {
    int v = 0;
    if (t >= d && t < 256) v = lscan[t - d];
    __syncthreads();
    if (t >= d && t < 256) lscan[t] += v;
    __syncthreads();
  }
  const int excl = lscan[t] - myv;
  if (t < nn) {
    offs[nb0 + t] = wbase + excl;
    dinv[nb0 + t] = rsqrtf((float)(myv + 1));
  }
  if (t == 0 && nb0 + nn == N) offs[N] = E;
  if (t < 256) ldeg[t] = excl;  // becomes local cursor
  __syncthreads();
  for (int i = t; i < cnt; i += 512) {
    unsigned v = ebuf[i];
    int pos = atomicAdd(&ldeg[v >> 17], 1);
    if (pos < BCAP) csr[wbase + pos] = (int)(v & 0x1FFFF);
  }
}

// ---------------------------------------------------------------------------
// Dense GEMM (layer 1): Y split [2][n][32] fp16 = X[N,128] @ W1[128,64].
// ---------------------------------------------------------------------------
template <int K, int M>
__global__ __launch_bounds__(256) void gemm_kernel(const float* __restrict__ X,
    const float* __restrict__ W, __half* __restrict__ Y, int n) {
  constexpr int RPB = 32;
  constexpr int XST = K + 4;
  constexpr int MC = M / 16;
  constexpr int HF = M / 2;
  __shared__ __align__(16) float Ws[K * M];
  __shared__ __align__(16) float Xs[RPB * XST];
  const int tid = threadIdx.x;
  const int row0 = blockIdx.x * RPB;
  for (int i = tid * 4; i < K * M; i += 1024)
    *reinterpret_cast<float4*>(&Ws[i]) = *reinterpret_cast<const float4*>(&W[i]);
  for (int i = tid * 4; i < RPB * K; i += 1024) {
    int r = i / K, k = i - r * K;
    int gr = row0 + r;
    float4 v = make_float4(0.f, 0.f, 0.f, 0.f);
    if (gr < n) v = *reinterpret_cast<const float4*>(&X[(size_t)gr * K + k]);
    *reinterpret_cast<float4*>(&Xs[r * XST + k]) = v;
  }
  __syncthreads();
  const int rt = tid & 15;
  const int c = tid >> 4;
  float acc[2][MC];
#pragma unroll
  for (int rr = 0; rr < 2; ++rr)
#pragma unroll
    for (int j = 0; j < MC; ++j) acc[rr][j] = 0.f;
  for (int k4 = 0; k4 < K; k4 += 4) {
    float4 xv[2];
#pragma unroll
    for (int rr = 0; rr < 2; ++rr)
      xv[rr] = *reinterpret_cast<const float4*>(&Xs[(rt + 16 * rr) * XST + k4]);
    const float* xf0 = reinterpret_cast<const float*>(&xv[0]);
    const float* xf1 = reinterpret_cast<const float*>(&xv[1]);
#pragma unroll
    for (int kk = 0; kk < 4; ++kk) {
      float w[MC];
#pragma unroll
      for (int j = 0; j < MC; ++j) w[j] = Ws[(k4 + kk) * M + c * MC + j];
      float x0 = xf0[kk], x1 = xf1[kk];
#pragma unroll
      for (int j = 0; j < MC; ++j) {
        acc[0][j] += x0 * w[j];
        acc[1][j] += x1 * w[j];
      }
    }
  }
  const int c0 = c * MC;             // 0,4,...,60 (stays within one half)
  const int oh = c0 / HF, oc = c0 - oh * HF;
#pragma unroll
  for (int rr = 0; rr < 2; ++rr) {
    int gr = row0 + rt + 16 * rr;
    if (gr < n) {
      union { __half hh[MC]; uint2 u2; } cv;
#pragma unroll
      for (int j = 0; j < MC; ++j) cv.hh[j] = __float2half(acc[rr][j]);
      *reinterpret_cast<uint2*>(Y + (size_t)oh * n * HF + (size_t)gr * HF + oc) = cv.u2;
    }
  }
}

// ---------------------------------------------------------------------------
// Fused GCN layer, split-gather: h is [2][n][32]; block = 64 nodes, 4 lanes
// per node own 8 feats (16B gathers); two half-phases (barrier between) ->
// chip-wide active gather array is one 6.4MB half. Then bias/relu -> LDS ->
// GEMM with W -> y split [2][n][FOUT/2] fp16.
// ---------------------------------------------------------------------------
__device__ inline void h8_acc(uint4 r, float w, float* acc) {
  const __half2* hp = reinterpret_cast<const __half2*>(&r);
#pragma unroll
  for (int q = 0; q < 4; ++q) {
    float2 f = __half22float2(hp[q]);
    acc[2 * q]     += w * f.x;
    acc[2 * q + 1] += w * f.y;
  }
}

template <int FOUT>
__global__ __launch_bounds__(256) void agg_gemm_kernel(
    const __half* __restrict__ h, const int* __restrict__ offs,
    const int* __restrict__ csr, const float* __restrict__ dinv,
    const float* __restrict__ bias, const float* __restrict__ W,
    __half* __restrict__ y, int n) {
  constexpr int FIN = 64;
  constexpr int XST = FIN + 4;
  __shared__ float Xs[64 * XST];                       // 17.4KB
  __shared__ __align__(16) float Wls[FIN * FOUT];
  const int t = threadIdx.x;
  for (int i = t * 4; i < FIN * FOUT; i += 1024)
    *reinterpret_cast<float4*>(&Wls[i]) = *reinterpret_cast<const float4*>(&W[i]);
  const int r = t >> 2;              // local node 0..63
  const int node = blockIdx.x * 64 + r;
  const int fl = (t & 3) * 8;        // feat offset within a 32-half
  int e0 = 0, e1 = 0;
  float di = 0.f;
  if (node < n) { e0 = offs[node]; e1 = offs[node + 1]; di = dinv[node]; }
  const size_t HS = (size_t)n * 32;  // half stride (fp16 elements)
#pragma unroll
  for (int half = 0; half < 2; ++half) {
    const __half* hh = h + (size_t)half * HS + fl;
    float acc[8];
#pragma unroll
    for (int j = 0; j < 8; ++j) acc[j] = 0.f;
    if (node < n) {
      {
        uint4 rr = *reinterpret_cast<const uint4*>(hh + (size_t)node * 32);
        h8_acc(rr, di * di, acc);
      }
      int e = e0;
      for (; e + 4 <= e1; e += 4) {
        int sidx[4];
        float wv[4];
        uint4 rv[4];
#pragma unroll
        for (int u = 0; u < 4; ++u) sidx[u] = csr[e + u];
#pragma unroll
        for (int u = 0; u < 4; ++u) wv[u] = di * dinv[sidx[u]];
#pragma unroll
        for (int u = 0; u < 4; ++u)
          rv[u] = *reinterpret_cast<const uint4*>(hh + (size_t)sidx[u] * 32);
#pragma unroll
        for (int u = 0; u < 4; ++u) h8_acc(rv[u], wv[u], acc);
      }
      for (; e < e1; ++e) {
        int s = csr[e];
        uint4 rr = *reinterpret_cast<const uint4*>(hh + (size_t)s * 32);
        h8_acc(rr, di * dinv[s], acc);
      }
      const int fb = half * 32 + fl;  // true feature base
#pragma unroll
      for (int j = 0; j < 8; ++j)
        Xs[r * XST + fb + j] = fmaxf(acc[j] + bias[fb + j], 0.f);
    }
    __syncthreads();  // phase-align the block (and free Xs hazard for epilogue)
  }
  // GEMM: 4 threads per node, CPT cols each
  constexpr int CPT = FOUT / 4;
  constexpr int HF = FOUT / 2;
  const int c0 = (t & 3) * CPT;
  float o[CPT];
#pragma unroll
  for (int j = 0; j < CPT; ++j) o[j] = 0.f;
  for (int k = 0; k < FIN; ++k) {
    const float xv = Xs[r * XST + k];
#pragma unroll
    for (int j4 = 0; j4 < CPT; j4 += 4) {
      float4 wv = *reinterpret_cast<const float4*>(&Wls[k * FOUT + c0 + j4]);
      o[j4] += xv * wv.x; o[j4 + 1] += xv * wv.y;
      o[j4 + 2] += xv * wv.z; o[j4 + 3] += xv * wv.w;
    }
  }
  if (node < n) {
    const int oh = c0 / HF, oc = c0 - oh * HF;
    union { __half hh[CPT]; uint4 u4[CPT / 8]; } cv;
#pragma unroll
    for (int j = 0; j < CPT; ++j) cv.hh[j] = __float2half(o[j]);
    uint4* dst4 = reinterpret_cast<uint4*>(y + (size_t)oh * n * HF +
                                           (size_t)node * HF + oc);
#pragma unroll
    for (int j = 0; j < CPT / 8; ++j) dst4[j] = cv.u4[j];
  }
}

// ---------------------------------------------------------------------------
// Layer-3 aggregate, split-gather (h = [2][n][16], halves 3.2MB: L2-fit)
// + bias/relu + hierarchical pool. Block = 128 nodes, 2 lanes/node.
// ---------------------------------------------------------------------------
__global__ __launch_bounds__(256) void agg_pool_kernel(const __half* __restrict__ h,
    const int* __restrict__ offs, const int* __restrict__ csr,
    const float* __restrict__ dinv, const float* __restrict__ bias,
    const int* __restrict__ batch, float* __restrict__ gsum, int n, int G) {
  constexpr int GCAP = 8;
  __shared__ float lg[GCAP * 32];
  const int t = threadIdx.x;
  const int node0 = blockIdx.x * 128;
  const int r = t >> 1;              // local node 0..127
  const int node = node0 + r;
  const int fl = (t & 1) * 8;        // feat offset within a 16-half
  for (int i = t; i < GCAP * 32; i += 256) lg[i] = 0.f;
  __syncthreads();
  const int g0 = batch[node0 < n ? node0 : (n - 1)];
  int e0 = 0, e1 = 0, g = -1, rel = 0;
  float di = 0.f;
  if (node < n) {
    e0 = offs[node]; e1 = offs[node + 1]; di = dinv[node];
    g = batch[node]; rel = g - g0;
  }
  const size_t HS = (size_t)n * 16;
#pragma unroll
  for (int half = 0; half < 2; ++half) {
    const __half* hh = h + (size_t)half * HS + fl;
    float acc[8];
#pragma unroll
    for (int j = 0; j < 8; ++j) acc[j] = 0.f;
    if (node < n) {
      {
        uint4 rr = *reinterpret_cast<const uint4*>(hh + (size_t)node * 16);
        h8_acc(rr, di * di, acc);
      }
      int e = e0;
      for (; e + 4 <= e1; e += 4) {
        int sidx[4];
        float wv[4];
        uint4 rv[4];
#pragma unroll
        for (int u = 0; u < 4; ++u) sidx[u] = csr[e + u];
#pragma unroll
        for (int u = 0; u < 4; ++u) wv[u] = di * dinv[sidx[u]];
#pragma unroll
        for (int u = 0; u < 4; ++u)
          rv[u] = *reinterpret_cast<const uint4*>(hh + (size_t)sidx[u] * 16);
#pragma unroll
        for (int u = 0; u < 4; ++u) h8_acc(rv[u], wv[u], acc);
      }
      for (; e < e1; ++e) {
        int s = csr[e];
        uint4 rr = *reinterpret_cast<const uint4*>(hh + (size_t)s * 16);
        h8_acc(rr, di * dinv[s], acc);
      }
      const int fb = half * 16 + fl;  // true feature base
      if (rel < GCAP) {
#pragma unroll
        for (int j = 0; j < 8; ++j)
          atomicAdd(&lg[rel * 32 + fb + j], fmaxf(acc[j] + bias[fb + j], 0.f));
      } else {  // pathological span: direct (rare)
#pragma unroll
        for (int j = 0; j < 8; ++j)
          atomicAdd(&gsum[(size_t)g * 32 + fb + j],
                    fmaxf(acc[j] + bias[fb + j], 0.f));
      }
    }
    __syncthreads();  // phase-align
  }
  for (int i = t; i < GCAP * 32; i += 256) {
    float v = lg[i];
    int gi = g0 * 32 + i;
    if (v != 0.f && gi < G * 32) atomicAdd(&gsum[gi], v);
  }
}

// One thread per graph: range via binary search, mean, MLP, log_softmax.
__global__ __launch_bounds__(256) void head_kernel(const float* __restrict__ gsum,
    const int* __restrict__ batch, const float* __restrict__ Wc1,
    const float* __restrict__ bc1, const float* __restrict__ Wc2,
    const float* __restrict__ bc2, float* __restrict__ out, int n, int G) {
  int g = blockIdx.x * blockDim.x + threadIdx.x;
  if (g >= G) return;
  int lo = 0, hi = n;
  while (lo < hi) { int m = (lo + hi) >> 1; if (batch[m] < g) lo = m + 1; else hi = m; }
  const int s0 = lo;
  lo = s0; hi = n;
  while (lo < hi) { int m = (lo + hi) >> 1; if (batch[m] < g + 1) lo = m + 1; else hi = m; }
  const float inv = 1.0f / fmaxf((float)(lo - s0), 1.0f);
  float p[32];
#pragma unroll
  for (int k = 0; k < 32; ++k) p[k] = gsum[g * 32 + k] * inv;
  float z[16];
#pragma unroll
  for (int j = 0; j < 16; ++j) {
    float a = bc1[j];
#pragma unroll
    for (int k = 0; k < 32; ++k) a += p[k] * Wc1[k * 16 + j];
    z[j] = fmaxf(a, 0.f);
  }
  float lg[16];
  float m = -1e30f;
#pragma unroll
  for (int j = 0; j < 16; ++j) {
    float a = bc2[j];
#pragma unroll
    for (int k = 0; k < 16; ++k) a += z[k] * Wc2[k * 16 + j];
    lg[j] = a;
    m = fmaxf(m, a);
  }
  float ssum = 0.f;
#pragma unroll
  for (int j = 0; j < 16; ++j) ssum += expf(lg[j] - m);
  float lse = logf(ssum);
#pragma unroll
  for (int j = 0; j < 16; ++j) out[g * 16 + j] = lg[j] - m - lse;
}

extern "C" void kernel_launch(void* const* d_in, const int* in_sizes, int n_in,
                              void* d_out, int out_size, void* d_ws, size_t ws_size,
                              hipStream_t stream) {
  const float* x   = (const float*)d_in[0];
  const int*   ei  = (const int*)d_in[1];
  const int*   batch = (const int*)d_in[2];
  const float* W1 = (const float*)d_in[3];
  const float* b1 = (const float*)d_in[4];
  const float* W2 = (const float*)d_in[5];
  const float* b2 = (const float*)d_in[6];
  const float* W3 = (const float*)d_in[7];
  const float* b3 = (const float*)d_in[8];
  const float* Wc1 = (const float*)d_in[9];
  const float* bc1 = (const float*)d_in[10];
  const float* Wc2 = (const float*)d_in[11];
  const float* bc2 = (const float*)d_in[12];

  const int N = in_sizes[2];        // 100000
  const int E = in_sizes[1] / 2;    // 3200000
  const int G = out_size / 16;      // 1024
  const int* src = ei;
  const int* dst = ei + E;
  const int nbuckets = (N + ((1 << BSHIFT) - 1)) >> BSHIFT;  // 391
  const int nblk = (E + EPB - 1) / EPB;                      // 782

  char* ws = (char*)d_ws;
  size_t off = 0;
  auto alloc = [&](size_t bytes) -> void* {
    void* p = ws + off;
    off += (bytes + 511) & ~(size_t)511;
    return p;
  };
  int*   offs   = (int*)alloc(((size_t)N + 1) * 4);
  float* dinv   = (float*)alloc((size_t)N * 4);
  int*   bucket_cnt  = (int*)alloc(2048);
  int*   bucket_base = (int*)alloc(2048);
  unsigned* runmap = (unsigned*)alloc((size_t)nbuckets * nblk * 4);  // 1.2MB
  int*   csr    = (int*)alloc((size_t)E * 4);
  __half* hbufA = (__half*)alloc((size_t)N * 64 * 2);   // layer1 out, [2][N][32]
  __half* hbufB = (__half*)alloc((size_t)N * 64 * 2);   // layer2 out, [2][N][32]
  __half* hbufC = (__half*)alloc((size_t)N * 32 * 2);   // layer3 out, [2][N][16]
  float* gsum   = (float*)alloc((size_t)G * 32 * 4);    // pooled sums
  // partition segments (E*4 = 12.8MB) alias hbufA (12.8MB): consumed by
  // fill_bucket before gemm1 writes hbufA.
  unsigned* part = (unsigned*)hbufA;
  (void)ws_size; (void)n_in;

  // --- CSR build (reused by all 3 layers) ---
  hipMemsetAsync(bucket_cnt, 0, (size_t)nbuckets * 4, stream);
  hipMemsetAsync(gsum, 0, (size_t)G * 32 * 4, stream);
  partition_kernel<<<nblk, 512, 0, stream>>>(src, dst, bucket_cnt, part, runmap,
                                             E, nbuckets, nblk);
  scan_buckets_kernel<<<1, 256, 0, stream>>>(bucket_cnt, bucket_base, nbuckets);
  fill_bucket_kernel<<<nbuckets, 512, 0, stream>>>(part, runmap, bucket_cnt,
                                                   bucket_base, offs, dinv, csr,
                                                   N, E, nblk);

  // --- layer 1 GEMM: x[N,128] @ W1 -> hbufA split fp16 ---
  gemm_kernel<128, 64><<<(N + 31) / 32, 256, 0, stream>>>(x, W1, hbufA, N);
  // --- fused layer1-agg + layer2-GEMM: hbufA -> hbufB ---
  agg_gemm_kernel<64><<<(N + 63) / 64, 256, 0, stream>>>(hbufA, offs, csr, dinv,
                                                         b1, W2, hbufB, N);
  // --- fused layer2-agg + layer3-GEMM: hbufB -> hbufC ---
  agg_gemm_kernel<32><<<(N + 63) / 64, 256, 0, stream>>>(hbufB, offs, csr, dinv,
                                                         b2, W3, hbufC, N);
  // --- layer3-agg + hierarchical pool ---
  agg_pool_kernel<<<(N + 127) / 128, 256, 0, stream>>>(hbufC, offs, csr, dinv,
                                                       b3, batch, gsum, N, G);
  // --- head: mean + MLP + log_softmax ---
  head_kernel<<<(G + 255) / 256, 256, 0, stream>>>(gsum, batch, Wc1, bc1,
                                                   Wc2, bc2, (float*)d_out, N, G);
}

// Round 13
// 349.698 us; speedup vs baseline: 1.3652x; 1.3559x over previous
//
#include <hip/hip_runtime.h>
#include <hip/hip_bf16.h>
#include <hip/hip_fp16.h>
#include <math.h>

// ---------------------------------------------------------------------------
// ActivityRecognitionGCN: 3x GCNConv(+ReLU) -> mean pool per graph -> MLP head
// N=100000 nodes, E=3.2M edges, G=1024 graphs, F: 128->64->64->32
// R12 -> R13: REVERT R11's split layout (64B half-rows broke 128B-line gather
// granularity: FETCH 170->253MB). Back to R10 (335.7us) + ONE change:
//  * fill_bucket places each node's edges in ascending src-slice order
//    (slice = src>>13 ~ 1MB of h). Degrees are ~32+-6, so all resident waves
//    at edge k gather from src quantile ~k/32: the chip-wide active gather
//    window is ~1-2MB (L2-fit) instead of 12.8MB -> fewer capacity misses.
// ---------------------------------------------------------------------------

constexpr int BSHIFT = 8;         // bucket = dst >> 8 (256 nodes per bucket)
constexpr int BMASK  = 255;
constexpr int BCAP   = 10240;     // bucket capacity (mean 8192, +22 sigma)
constexpr int EPB    = 4096;      // edges per partition block
constexpr int SLICE_SHIFT = 13;   // src slice = 8192 nodes (~1MB @ F=64 fp16)

// Per-block LDS counting sort by bucket; coalesced segment write + run map.
__global__ __launch_bounds__(512) void partition_kernel(const int* __restrict__ src,
    const int* __restrict__ dst, int* __restrict__ bucket_cnt,
    unsigned* __restrict__ part, unsigned* __restrict__ runmap,
    int E, int nbuckets, int nblk) {
  __shared__ int lcnt[512];
  __shared__ int lscan[512];
  __shared__ int lcur[512];
  __shared__ unsigned spay[EPB];
  const int t = threadIdx.x;
  const int blk = blockIdx.x;
  const int base = blk * EPB;
  const int lim = min(EPB, E - base);
  int s[8], d[8];
#pragma unroll
  for (int j = 0; j < 8; ++j) {
    int idx = base + j * 512 + t;
    if (idx < E) { s[j] = src[idx]; d[j] = dst[idx]; } else d[j] = -1;
  }
  lcnt[t] = 0;
  __syncthreads();
#pragma unroll
  for (int j = 0; j < 8; ++j)
    if (d[j] >= 0) atomicAdd(&lcnt[d[j] >> BSHIFT], 1);
  __syncthreads();
  const int myv = lcnt[t];
  lscan[t] = myv;
  __syncthreads();
  for (int dd = 1; dd < 512; dd <<= 1) {
    int v = 0;
    if (t >= dd) v = lscan[t - dd];
    __syncthreads();
    if (t >= dd) lscan[t] += v;
    __syncthreads();
  }
  const int excl = lscan[t] - myv;
  if (t < nbuckets) {
    runmap[(size_t)t * nblk + blk] = (unsigned)excl | ((unsigned)myv << 16);
    if (myv > 0) atomicAdd(&bucket_cnt[t], myv);
  }
  lcur[t] = excl;
  __syncthreads();
#pragma unroll
  for (int j = 0; j < 8; ++j) {
    if (d[j] >= 0) {
      int b = d[j] >> BSHIFT;
      int pos = atomicAdd(&lcur[b], 1);
      spay[pos] = ((unsigned)(d[j] & BMASK) << 17) | (unsigned)s[j];
    }
  }
  __syncthreads();
#pragma unroll
  for (int j = 0; j < 8; ++j) {
    int i = j * 512 + t;
    if (i < lim) part[base + i] = spay[i];
  }
}

// Exclusive scan of bucket_cnt (nb <= 512) in a single block.
__global__ __launch_bounds__(256) void scan_buckets_kernel(const int* __restrict__ cnt,
    int* __restrict__ base, int nb) {
  __shared__ int sh[512];
  const int t = threadIdx.x;
  sh[t] = (t < nb) ? cnt[t] : 0;
  sh[t + 256] = (t + 256 < nb) ? cnt[t + 256] : 0;
  __syncthreads();
  for (int d = 1; d < 512; d <<= 1) {
    int v0 = 0, v1 = 0;
    if (t >= d) v0 = sh[t - d];
    if (t + 256 >= d) v1 = sh[t + 256 - d];
    __syncthreads();
    if (t >= d) sh[t] += v0;
    if (t + 256 >= d) sh[t + 256] += v1;
    __syncthreads();
  }
  if (t < nb) base[t] = (t == 0) ? 0 : sh[t - 1];
  if (t + 256 < nb) base[t + 256] = sh[t + 255];
}

// One block (512 thr) per bucket: stage runs -> LDS once, degree hist, scan
// (offs/dinv), then SRC-SLICE-ORDERED placement into the csr window (13
// filtered LDS passes; scattered stores stay in the 32KB single-XCD window).
__global__ __launch_bounds__(512) void fill_bucket_kernel(
    const unsigned* __restrict__ part, const unsigned* __restrict__ runmap,
    const int* __restrict__ bucket_cnt, const int* __restrict__ bucket_base,
    int* __restrict__ offs, float* __restrict__ dinv, int* __restrict__ csr,
    int N, int E, int nblk) {
  __shared__ unsigned ebuf[BCAP];
  __shared__ int rsh[1024];
  __shared__ int ldeg[256];
  __shared__ int lscan[512];
  const int b = blockIdx.x;
  const int t = threadIdx.x;
  const int nb0 = b << BSHIFT;
  const int nn = min(1 << BSHIFT, N - nb0);
  const int wbase = bucket_base[b];
  const int cnt = min(bucket_cnt[b], BCAP);
  const unsigned r0 = (t < nblk) ? runmap[(size_t)b * nblk + t] : 0u;
  const unsigned r1 = (t + 512 < nblk) ? runmap[(size_t)b * nblk + t + 512] : 0u;
  const int c0 = (int)(r0 >> 16), c1 = (int)(r1 >> 16);
  rsh[t] = c0; rsh[t + 512] = c1;
  if (t < 256) ldeg[t] = 0;
  __syncthreads();
  for (int dd = 1; dd < 1024; dd <<= 1) {
    int x0 = 0, x1 = 0;
    if (t >= dd) x0 = rsh[t - dd];
    x1 = rsh[t + 512 - dd];
    __syncthreads();
    if (t >= dd) rsh[t] += x0;
    rsh[t + 512] += x1;
    __syncthreads();
  }
  {  // stage runs into ebuf (the ONLY scattered-read pass)
    int rb = rsh[t] - c0;
    if (c0 > 0) {
      const unsigned* p = part + (size_t)t * EPB + (r0 & 0xFFFFu);
      for (int k = 0; k < c0; ++k) { int o = rb + k; if (o < BCAP) ebuf[o] = p[k]; }
    }
    int rb1 = rsh[t + 512] - c1;
    if (c1 > 0) {
      const unsigned* p = part + (size_t)(t + 512) * EPB + (r1 & 0xFFFFu);
      for (int k = 0; k < c1; ++k) { int o = rb1 + k; if (o < BCAP) ebuf[o] = p[k]; }
    }
  }
  __syncthreads();
  for (int i = t; i < cnt; i += 512) atomicAdd(&ldeg[ebuf[i] >> 17], 1);
  __syncthreads();
  const int myv = (t < 256) ? ldeg[t] : 0;
  lscan[t] = myv;
  __syncthreads();
  for (int d = 1; d < 256; d <<= 1) {
    int v = 0;
    if (t >= d && t < 256) v = lscan[t - d];
    __syncthreads();
    if (t >= d && t < 256) lscan[t] += v;
    __syncthreads();
  }
  const int excl = lscan[t] - myv;
  if (t < nn) {
    offs[nb0 + t] = wbase + excl;
    dinv[nb0 + t] = rsqrtf((float)(myv + 1));
  }
  if (t == 0 && nb0 + nn == N) offs[N] = E;
  if (t < 256) ldeg[t] = excl;  // becomes local cursor
  __syncthreads();
  // src-slice-ordered placement: pass p places edges with src-slice == p.
  const int nslices = (N + (1 << SLICE_SHIFT) - 1) >> SLICE_SHIFT;  // 13
  for (int p = 0; p < nslices; ++p) {
    for (int i = t; i < cnt; i += 512) {
      unsigned v = ebuf[i];
      if ((int)((v & 0x1FFFFu) >> SLICE_SHIFT) == p) {
        int pos = atomicAdd(&ldeg[v >> 17], 1);
        if (pos < BCAP) csr[wbase + pos] = (int)(v & 0x1FFFF);
      }
    }
    __syncthreads();  // pass p fully placed before p+1 (keeps per-node order)
  }
}

// ---------------------------------------------------------------------------
// Dense GEMM (layer 1 only): Y[N,64](fp16) = X[N,128](fp32) @ W1.
// ---------------------------------------------------------------------------
template <int K, int M>
__global__ __launch_bounds__(256) void gemm_kernel(const float* __restrict__ X,
    const float* __restrict__ W, __half* __restrict__ Y, int n) {
  constexpr int RPB = 32;
  constexpr int XST = K + 4;
  constexpr int MC = M / 16;
  __shared__ __align__(16) float Ws[K * M];
  __shared__ __align__(16) float Xs[RPB * XST];
  const int tid = threadIdx.x;
  const int row0 = blockIdx.x * RPB;
  for (int i = tid * 4; i < K * M; i += 1024)
    *reinterpret_cast<float4*>(&Ws[i]) = *reinterpret_cast<const float4*>(&W[i]);
  for (int i = tid * 4; i < RPB * K; i += 1024) {
    int r = i / K, k = i - r * K;
    int gr = row0 + r;
    float4 v = make_float4(0.f, 0.f, 0.f, 0.f);
    if (gr < n) v = *reinterpret_cast<const float4*>(&X[(size_t)gr * K + k]);
    *reinterpret_cast<float4*>(&Xs[r * XST + k]) = v;
  }
  __syncthreads();
  const int rt = tid & 15;
  const int c = tid >> 4;
  float acc[2][MC];
#pragma unroll
  for (int rr = 0; rr < 2; ++rr)
#pragma unroll
    for (int j = 0; j < MC; ++j) acc[rr][j] = 0.f;
  for (int k4 = 0; k4 < K; k4 += 4) {
    float4 xv[2];
#pragma unroll
    for (int rr = 0; rr < 2; ++rr)
      xv[rr] = *reinterpret_cast<const float4*>(&Xs[(rt + 16 * rr) * XST + k4]);
    const float* xf0 = reinterpret_cast<const float*>(&xv[0]);
    const float* xf1 = reinterpret_cast<const float*>(&xv[1]);
#pragma unroll
    for (int kk = 0; kk < 4; ++kk) {
      float w[MC];
#pragma unroll
      for (int j = 0; j < MC; ++j) w[j] = Ws[(k4 + kk) * M + c * MC + j];
      float x0 = xf0[kk], x1 = xf1[kk];
#pragma unroll
      for (int j = 0; j < MC; ++j) {
        acc[0][j] += x0 * w[j];
        acc[1][j] += x1 * w[j];
      }
    }
  }
#pragma unroll
  for (int rr = 0; rr < 2; ++rr) {
    int gr = row0 + rt + 16 * rr;
    if (gr < n) {
#pragma unroll
      for (int j = 0; j < MC; ++j)
        Y[(size_t)gr * M + c * MC + j] = __float2half(acc[rr][j]);
    }
  }
}

// ---------------------------------------------------------------------------
// Fused GCN layer: out_row = relu(agg(h) + bias); y = out_row @ W (fp16).
// Block = 32 nodes; 8 lanes/node own 8 features each (16B gathers).
// ---------------------------------------------------------------------------
__device__ inline void h8_acc(uint4 r, float w, float* acc) {
  const __half2* hp = reinterpret_cast<const __half2*>(&r);
#pragma unroll
  for (int q = 0; q < 4; ++q) {
    float2 f = __half22float2(hp[q]);
    acc[2 * q]     += w * f.x;
    acc[2 * q + 1] += w * f.y;
  }
}

template <int FOUT>
__global__ __launch_bounds__(256) void agg_gemm_kernel(
    const __half* __restrict__ h, const int* __restrict__ offs,
    const int* __restrict__ csr, const float* __restrict__ dinv,
    const float* __restrict__ bias, const float* __restrict__ W,
    __half* __restrict__ y, int n) {
  constexpr int FIN = 64;
  constexpr int XST = FIN + 4;
  __shared__ float Xs[32 * XST];
  __shared__ __align__(16) float Wls[FIN * FOUT];
  const int t = threadIdx.x;
  for (int i = t * 4; i < FIN * FOUT; i += 1024)
    *reinterpret_cast<float4*>(&Wls[i]) = *reinterpret_cast<const float4*>(&W[i]);
  const int r = t >> 3;            // local node 0..31
  const int node = blockIdx.x * 32 + r;
  const int fl = (t & 7) * 8;
  float acc[8];
#pragma unroll
  for (int j = 0; j < 8; ++j) acc[j] = 0.f;
  if (node < n) {
    const int e0 = offs[node], e1 = offs[node + 1];
    const float di = dinv[node];
    {
      uint4 rr = *reinterpret_cast<const uint4*>(h + (size_t)node * FIN + fl);
      h8_acc(rr, di * di, acc);
    }
    int e = e0;
    for (; e + 4 <= e1; e += 4) {
      int sidx[4];
      float wv[4];
      uint4 rv[4];
#pragma unroll
      for (int u = 0; u < 4; ++u) sidx[u] = csr[e + u];
#pragma unroll
      for (int u = 0; u < 4; ++u) wv[u] = di * dinv[sidx[u]];
#pragma unroll
      for (int u = 0; u < 4; ++u)
        rv[u] = *reinterpret_cast<const uint4*>(h + (size_t)sidx[u] * FIN + fl);
#pragma unroll
      for (int u = 0; u < 4; ++u) h8_acc(rv[u], wv[u], acc);
    }
    for (; e < e1; ++e) {
      int s = csr[e];
      uint4 rr = *reinterpret_cast<const uint4*>(h + (size_t)s * FIN + fl);
      h8_acc(rr, di * dinv[s], acc);
    }
#pragma unroll
    for (int j = 0; j < 8; ++j)
      Xs[r * XST + fl + j] = fmaxf(acc[j] + bias[fl + j], 0.f);
  }
  __syncthreads();
  // GEMM: thread computes its node's cols c0..c0+CPT-1
  constexpr int CPT = FOUT / 8;
  const int c0 = (t & 7) * CPT;
  float a2[CPT];
#pragma unroll
  for (int j = 0; j < CPT; ++j) a2[j] = 0.f;
  for (int k = 0; k < FIN; ++k) {
    float xv = Xs[r * XST + k];
    const float4 wa = *reinterpret_cast<const float4*>(&Wls[k * FOUT + c0]);
    a2[0] += xv * wa.x; a2[1] += xv * wa.y;
    a2[2] += xv * wa.z; a2[3] += xv * wa.w;
    if constexpr (CPT == 8) {
      const float4 wb = *reinterpret_cast<const float4*>(&Wls[k * FOUT + c0 + 4]);
      a2[4] += xv * wb.x; a2[5] += xv * wb.y;
      a2[6] += xv * wb.z; a2[7] += xv * wb.w;
    }
  }
  if (node < n) {
    union { __half hh[CPT]; uint4 u4; uint2 u2; } cv;
#pragma unroll
    for (int j = 0; j < CPT; ++j) cv.hh[j] = __float2half(a2[j]);
    if constexpr (CPT == 8)
      *reinterpret_cast<uint4*>(y + (size_t)node * FOUT + c0) = cv.u4;
    else
      *reinterpret_cast<uint2*>(y + (size_t)node * FOUT + c0) = cv.u2;
  }
}

// ---------------------------------------------------------------------------
// Layer 3 aggregate (F=32) + relu/bias + hierarchical pool: LDS per-graph
// window (batch sorted -> a 64-node block spans ~1-3 graphs), one flush.
// ---------------------------------------------------------------------------
__global__ __launch_bounds__(256) void agg_pool_kernel(const __half* __restrict__ h,
    const int* __restrict__ offs, const int* __restrict__ csr,
    const float* __restrict__ dinv, const float* __restrict__ bias,
    const int* __restrict__ batch, float* __restrict__ gsum, int n, int G) {
  constexpr int F = 32;
  constexpr int GCAP = 8;
  __shared__ float lg[GCAP * F];
  const int t = threadIdx.x;
  const int node0 = blockIdx.x * 64;
  const int node = node0 + (t >> 2);
  const int fl = (t & 3) * 8;
  for (int i = t; i < GCAP * F; i += 256) lg[i] = 0.f;
  __syncthreads();
  const int g0 = batch[node0 < n ? node0 : (n - 1)];
  if (node < n) {
    const int e0 = offs[node], e1 = offs[node + 1];
    const float di = dinv[node];
    float acc[8];
#pragma unroll
    for (int j = 0; j < 8; ++j) acc[j] = 0.f;
    {
      uint4 rr = *reinterpret_cast<const uint4*>(h + (size_t)node * F + fl);
      h8_acc(rr, di * di, acc);
    }
    int e = e0;
    for (; e + 4 <= e1; e += 4) {
      int sidx[4];
      float wv[4];
      uint4 rv[4];
#pragma unroll
      for (int u = 0; u < 4; ++u) sidx[u] = csr[e + u];
#pragma unroll
      for (int u = 0; u < 4; ++u) wv[u] = di * dinv[sidx[u]];
#pragma unroll
      for (int u = 0; u < 4; ++u)
        rv[u] = *reinterpret_cast<const uint4*>(h + (size_t)sidx[u] * F + fl);
#pragma unroll
      for (int u = 0; u < 4; ++u) h8_acc(rv[u], wv[u], acc);
    }
    for (; e < e1; ++e) {
      int s = csr[e];
      uint4 rr = *reinterpret_cast<const uint4*>(h + (size_t)s * F + fl);
      h8_acc(rr, di * dinv[s], acc);
    }
    const int rel = batch[node] - g0;
    if (rel < GCAP) {
#pragma unroll
      for (int j = 0; j < 8; ++j)
        atomicAdd(&lg[rel * F + fl + j], fmaxf(acc[j] + bias[fl + j], 0.f));
    } else {  // pathological span: direct (rare)
      float* gp = gsum + (size_t)batch[node] * F + fl;
#pragma unroll
      for (int j = 0; j < 8; ++j)
        atomicAdd(&gp[j], fmaxf(acc[j] + bias[fl + j], 0.f));
    }
  }
  __syncthreads();
  for (int i = t; i < GCAP * F; i += 256) {
    float v = lg[i];
    int gi = g0 * F + i;
    if (v != 0.f && gi < G * F) atomicAdd(&gsum[gi], v);
  }
}

// One thread per graph: range via binary search, mean, MLP, log_softmax.
__global__ __launch_bounds__(256) void head_kernel(const float* __restrict__ gsum,
    const int* __restrict__ batch, const float* __restrict__ Wc1,
    const float* __restrict__ bc1, const float* __restrict__ Wc2,
    const float* __restrict__ bc2, float* __restrict__ out, int n, int G) {
  int g = blockIdx.x * blockDim.x + threadIdx.x;
  if (g >= G) return;
  int lo = 0, hi = n;
  while (lo < hi) { int m = (lo + hi) >> 1; if (batch[m] < g) lo = m + 1; else hi = m; }
  const int s0 = lo;
  lo = s0; hi = n;
  while (lo < hi) { int m = (lo + hi) >> 1; if (batch[m] < g + 1) lo = m + 1; else hi = m; }
  const float inv = 1.0f / fmaxf((float)(lo - s0), 1.0f);
  float p[32];
#pragma unroll
  for (int k = 0; k < 32; ++k) p[k] = gsum[g * 32 + k] * inv;
  float z[16];
#pragma unroll
  for (int j = 0; j < 16; ++j) {
    float a = bc1[j];
#pragma unroll
    for (int k = 0; k < 32; ++k) a += p[k] * Wc1[k * 16 + j];
    z[j] = fmaxf(a, 0.f);
  }
  float lg[16];
  float m = -1e30f;
#pragma unroll
  for (int j = 0; j < 16; ++j) {
    float a = bc2[j];
#pragma unroll
    for (int k = 0; k < 16; ++k) a += z[k] * Wc2[k * 16 + j];
    lg[j] = a;
    m = fmaxf(m, a);
  }
  float ssum = 0.f;
#pragma unroll
  for (int j = 0; j < 16; ++j) ssum += expf(lg[j] - m);
  float lse = logf(ssum);
#pragma unroll
  for (int j = 0; j < 16; ++j) out[g * 16 + j] = lg[j] - m - lse;
}

extern "C" void kernel_launch(void* const* d_in, const int* in_sizes, int n_in,
                              void* d_out, int out_size, void* d_ws, size_t ws_size,
                              hipStream_t stream) {
  const float* x   = (const float*)d_in[0];
  const int*   ei  = (const int*)d_in[1];
  const int*   batch = (const int*)d_in[2];
  const float* W1 = (const float*)d_in[3];
  const float* b1 = (const float*)d_in[4];
  const float* W2 = (const float*)d_in[5];
  const float* b2 = (const float*)d_in[6];
  const float* W3 = (const float*)d_in[7];
  const float* b3 = (const float*)d_in[8];
  const float* Wc1 = (const float*)d_in[9];
  const float* bc1 = (const float*)d_in[10];
  const float* Wc2 = (const float*)d_in[11];
  const float* bc2 = (const float*)d_in[12];

  const int N = in_sizes[2];        // 100000
  const int E = in_sizes[1] / 2;    // 3200000
  const int G = out_size / 16;      // 1024
  const int* src = ei;
  const int* dst = ei + E;
  const int nbuckets = (N + ((1 << BSHIFT) - 1)) >> BSHIFT;  // 391
  const int nblk = (E + EPB - 1) / EPB;                      // 782

  char* ws = (char*)d_ws;
  size_t off = 0;
  auto alloc = [&](size_t bytes) -> void* {
    void* p = ws + off;
    off += (bytes + 511) & ~(size_t)511;
    return p;
  };
  int*   offs   = (int*)alloc(((size_t)N + 1) * 4);
  float* dinv   = (float*)alloc((size_t)N * 4);
  int*   bucket_cnt  = (int*)alloc(2048);
  int*   bucket_base = (int*)alloc(2048);
  unsigned* runmap = (unsigned*)alloc((size_t)nbuckets * nblk * 4);  // 1.2MB
  int*   csr    = (int*)alloc((size_t)E * 4);
  __half* hbufA = (__half*)alloc((size_t)N * 64 * 2);   // layer1 gemm out
  __half* hbufB = (__half*)alloc((size_t)N * 64 * 2);   // layer2 fused out
  __half* hbufC = (__half*)alloc((size_t)N * 32 * 2);   // layer3 fused out
  float* gsum   = (float*)alloc((size_t)G * 32 * 4);    // pooled sums
  // partition segments (E*4 = 12.8MB) alias hbufA (12.8MB): consumed by
  // fill_bucket before gemm1 writes hbufA.
  unsigned* part = (unsigned*)hbufA;
  (void)ws_size; (void)n_in;

  // --- CSR build (reused by all 3 layers) ---
  hipMemsetAsync(bucket_cnt, 0, (size_t)nbuckets * 4, stream);
  hipMemsetAsync(gsum, 0, (size_t)G * 32 * 4, stream);
  partition_kernel<<<nblk, 512, 0, stream>>>(src, dst, bucket_cnt, part, runmap,
                                             E, nbuckets, nblk);
  scan_buckets_kernel<<<1, 256, 0, stream>>>(bucket_cnt, bucket_base, nbuckets);
  fill_bucket_kernel<<<nbuckets, 512, 0, stream>>>(part, runmap, bucket_cnt,
                                                   bucket_base, offs, dinv, csr,
                                                   N, E, nblk);

  // --- layer 1 GEMM: x[N,128] @ W1 -> hbufA fp16 ---
  gemm_kernel<128, 64><<<(N + 31) / 32, 256, 0, stream>>>(x, W1, hbufA, N);
  // --- fused layer1-agg + layer2-GEMM: hbufA -> hbufB ---
  agg_gemm_kernel<64><<<(N + 31) / 32, 256, 0, stream>>>(hbufA, offs, csr, dinv,
                                                         b1, W2, hbufB, N);
  // --- fused layer2-agg + layer3-GEMM: hbufB -> hbufC ---
  agg_gemm_kernel<32><<<(N + 31) / 32, 256, 0, stream>>>(hbufB, offs, csr, dinv,
                                                         b2, W3, hbufC, N);
  // --- layer3-agg + hierarchical pool ---
  agg_pool_kernel<<<(N + 63) / 64, 256, 0, stream>>>(hbufC, offs, csr, dinv,
                                                     b3, batch, gsum, N, G);
  // --- head: mean + MLP + log_softmax ---
  head_kernel<<<(G + 255) / 256, 256, 0, stream>>>(gsum, batch, Wc1, bc1,
                                                   Wc2, bc2, (float*)d_out, N, G);
}

// Round 14
// 327.566 us; speedup vs baseline: 1.4574x; 1.0676x over previous
//
#include <hip/hip_runtime.h>
#include <hip/hip_bf16.h>
#include <hip/hip_fp16.h>
#include <math.h>

// ---------------------------------------------------------------------------
// ActivityRecognitionGCN: 3x GCNConv(+ReLU) -> mean pool per graph -> MLP head
// N=100000 nodes, E=3.2M edges, G=1024 graphs, F: 128->64->64->32
// R13 -> R14: keep src-slice-ordered edges (agg FETCH 170->153MB, -2.7us/agg,
// confirmed), but produce the order in ONE placement pass:
//  * fill_bucket: 2D LDS histogram cnt2[node][slice] (256x13 = 13.3KB);
//    per-node degree = serial sum of 13; per-node serial prefix over slices;
//    single placement pass via atomicAdd on cnt2. R13's 13 filtered passes
//    cost +20us; this restores R10's fill cost with R13's edge order.
// ---------------------------------------------------------------------------

constexpr int BSHIFT = 8;         // bucket = dst >> 8 (256 nodes per bucket)
constexpr int BMASK  = 255;
constexpr int BCAP   = 10240;     // bucket capacity (mean 8192, +22 sigma)
constexpr int EPB    = 4096;      // edges per partition block
constexpr int SLICE_SHIFT = 13;   // src slice = 8192 nodes (~1MB @ F=64 fp16)
constexpr int NSLICES = 13;       // ceil(100000 / 8192)

// Per-block LDS counting sort by bucket; coalesced segment write + run map.
__global__ __launch_bounds__(512) void partition_kernel(const int* __restrict__ src,
    const int* __restrict__ dst, int* __restrict__ bucket_cnt,
    unsigned* __restrict__ part, unsigned* __restrict__ runmap,
    int E, int nbuckets, int nblk) {
  __shared__ int lcnt[512];
  __shared__ int lscan[512];
  __shared__ int lcur[512];
  __shared__ unsigned spay[EPB];
  const int t = threadIdx.x;
  const int blk = blockIdx.x;
  const int base = blk * EPB;
  const int lim = min(EPB, E - base);
  int s[8], d[8];
#pragma unroll
  for (int j = 0; j < 8; ++j) {
    int idx = base + j * 512 + t;
    if (idx < E) { s[j] = src[idx]; d[j] = dst[idx]; } else d[j] = -1;
  }
  lcnt[t] = 0;
  __syncthreads();
#pragma unroll
  for (int j = 0; j < 8; ++j)
    if (d[j] >= 0) atomicAdd(&lcnt[d[j] >> BSHIFT], 1);
  __syncthreads();
  const int myv = lcnt[t];
  lscan[t] = myv;
  __syncthreads();
  for (int dd = 1; dd < 512; dd <<= 1) {
    int v = 0;
    if (t >= dd) v = lscan[t - dd];
    __syncthreads();
    if (t >= dd) lscan[t] += v;
    __syncthreads();
  }
  const int excl = lscan[t] - myv;
  if (t < nbuckets) {
    runmap[(size_t)t * nblk + blk] = (unsigned)excl | ((unsigned)myv << 16);
    if (myv > 0) atomicAdd(&bucket_cnt[t], myv);
  }
  lcur[t] = excl;
  __syncthreads();
#pragma unroll
  for (int j = 0; j < 8; ++j) {
    if (d[j] >= 0) {
      int b = d[j] >> BSHIFT;
      int pos = atomicAdd(&lcur[b], 1);
      spay[pos] = ((unsigned)(d[j] & BMASK) << 17) | (unsigned)s[j];
    }
  }
  __syncthreads();
#pragma unroll
  for (int j = 0; j < 8; ++j) {
    int i = j * 512 + t;
    if (i < lim) part[base + i] = spay[i];
  }
}

// Exclusive scan of bucket_cnt (nb <= 512) in a single block.
__global__ __launch_bounds__(256) void scan_buckets_kernel(const int* __restrict__ cnt,
    int* __restrict__ base, int nb) {
  __shared__ int sh[512];
  const int t = threadIdx.x;
  sh[t] = (t < nb) ? cnt[t] : 0;
  sh[t + 256] = (t + 256 < nb) ? cnt[t + 256] : 0;
  __syncthreads();
  for (int d = 1; d < 512; d <<= 1) {
    int v0 = 0, v1 = 0;
    if (t >= d) v0 = sh[t - d];
    if (t + 256 >= d) v1 = sh[t + 256 - d];
    __syncthreads();
    if (t >= d) sh[t] += v0;
    if (t + 256 >= d) sh[t + 256] += v1;
    __syncthreads();
  }
  if (t < nb) base[t] = (t == 0) ? 0 : sh[t - 1];
  if (t + 256 < nb) base[t + 256] = sh[t + 255];
}

// One block (512 thr) per bucket: stage runs -> LDS once, (node,slice)
// histogram, per-node scan, ONE slice-ordered placement pass into the 32KB
// csr window (single-XCD L2-local stores).
__global__ __launch_bounds__(512) void fill_bucket_kernel(
    const unsigned* __restrict__ part, const unsigned* __restrict__ runmap,
    const int* __restrict__ bucket_cnt, const int* __restrict__ bucket_base,
    int* __restrict__ offs, float* __restrict__ dinv, int* __restrict__ csr,
    int N, int E, int nblk) {
  __shared__ unsigned ebuf[BCAP];          // 40KB
  __shared__ int rsh[1024];                // 4KB
  __shared__ int cnt2[256 * NSLICES];      // 13.3KB
  __shared__ int lscan[512];               // 2KB
  const int b = blockIdx.x;
  const int t = threadIdx.x;
  const int nb0 = b << BSHIFT;
  const int nn = min(1 << BSHIFT, N - nb0);
  const int wbase = bucket_base[b];
  const int cnt = min(bucket_cnt[b], BCAP);
  const unsigned r0 = (t < nblk) ? runmap[(size_t)b * nblk + t] : 0u;
  const unsigned r1 = (t + 512 < nblk) ? runmap[(size_t)b * nblk + t + 512] : 0u;
  const int c0 = (int)(r0 >> 16), c1 = (int)(r1 >> 16);
  rsh[t] = c0; rsh[t + 512] = c1;
  for (int i = t; i < 256 * NSLICES; i += 512) cnt2[i] = 0;
  __syncthreads();
  for (int dd = 1; dd < 1024; dd <<= 1) {
    int x0 = 0, x1 = 0;
    if (t >= dd) x0 = rsh[t - dd];
    x1 = rsh[t + 512 - dd];
    __syncthreads();
    if (t >= dd) rsh[t] += x0;
    rsh[t + 512] += x1;
    __syncthreads();
  }
  {  // stage runs into ebuf (the ONLY scattered-read pass)
    int rb = rsh[t] - c0;
    if (c0 > 0) {
      const unsigned* p = part + (size_t)t * EPB + (r0 & 0xFFFFu);
      for (int k = 0; k < c0; ++k) { int o = rb + k; if (o < BCAP) ebuf[o] = p[k]; }
    }
    int rb1 = rsh[t + 512] - c1;
    if (c1 > 0) {
      const unsigned* p = part + (size_t)(t + 512) * EPB + (r1 & 0xFFFFu);
      for (int k = 0; k < c1; ++k) { int o = rb1 + k; if (o < BCAP) ebuf[o] = p[k]; }
    }
  }
  __syncthreads();
  // (node, slice) histogram
  for (int i = t; i < cnt; i += 512) {
    unsigned v = ebuf[i];
    int sl = min((int)((v & 0x1FFFFu) >> SLICE_SHIFT), NSLICES - 1);
    atomicAdd(&cnt2[(v >> 17) * NSLICES + sl], 1);
  }
  __syncthreads();
  // per-node degree (serial sum of NSLICES counters)
  int myv = 0;
  if (t < 256) {
#pragma unroll
    for (int s = 0; s < NSLICES; ++s) myv += cnt2[t * NSLICES + s];
  }
  lscan[t] = myv;
  __syncthreads();
  for (int d = 1; d < 256; d <<= 1) {
    int v = 0;
    if (t >= d && t < 256) v = lscan[t - d];
    __syncthreads();
    if (t >= d && t < 256) lscan[t] += v;
    __syncthreads();
  }
  const int excl = lscan[t] - myv;
  if (t < nn) {
    offs[nb0 + t] = wbase + excl;
    dinv[nb0 + t] = rsqrtf((float)(myv + 1));
  }
  if (t == 0 && nb0 + nn == N) offs[N] = E;
  // per-node serial prefix across its slice counters -> cursors
  if (t < 256) {
    int running = excl;
#pragma unroll
    for (int s = 0; s < NSLICES; ++s) {
      int c = cnt2[t * NSLICES + s];
      cnt2[t * NSLICES + s] = running;
      running += c;
    }
  }
  __syncthreads();
  // single slice-ordered placement pass (stores into 32KB window, L2-local)
  for (int i = t; i < cnt; i += 512) {
    unsigned v = ebuf[i];
    int sl = min((int)((v & 0x1FFFFu) >> SLICE_SHIFT), NSLICES - 1);
    int pos = atomicAdd(&cnt2[(v >> 17) * NSLICES + sl], 1);
    if (pos < BCAP) csr[wbase + pos] = (int)(v & 0x1FFFF);
  }
}

// ---------------------------------------------------------------------------
// Dense GEMM (layer 1 only): Y[N,64](fp16) = X[N,128](fp32) @ W1.
// ---------------------------------------------------------------------------
template <int K, int M>
__global__ __launch_bounds__(256) void gemm_kernel(const float* __restrict__ X,
    const float* __restrict__ W, __half* __restrict__ Y, int n) {
  constexpr int RPB = 32;
  constexpr int XST = K + 4;
  constexpr int MC = M / 16;
  __shared__ __align__(16) float Ws[K * M];
  __shared__ __align__(16) float Xs[RPB * XST];
  const int tid = threadIdx.x;
  const int row0 = blockIdx.x * RPB;
  for (int i = tid * 4; i < K * M; i += 1024)
    *reinterpret_cast<float4*>(&Ws[i]) = *reinterpret_cast<const float4*>(&W[i]);
  for (int i = tid * 4; i < RPB * K; i += 1024) {
    int r = i / K, k = i - r * K;
    int gr = row0 + r;
    float4 v = make_float4(0.f, 0.f, 0.f, 0.f);
    if (gr < n) v = *reinterpret_cast<const float4*>(&X[(size_t)gr * K + k]);
    *reinterpret_cast<float4*>(&Xs[r * XST + k]) = v;
  }
  __syncthreads();
  const int rt = tid & 15;
  const int c = tid >> 4;
  float acc[2][MC];
#pragma unroll
  for (int rr = 0; rr < 2; ++rr)
#pragma unroll
    for (int j = 0; j < MC; ++j) acc[rr][j] = 0.f;
  for (int k4 = 0; k4 < K; k4 += 4) {
    float4 xv[2];
#pragma unroll
    for (int rr = 0; rr < 2; ++rr)
      xv[rr] = *reinterpret_cast<const float4*>(&Xs[(rt + 16 * rr) * XST + k4]);
    const float* xf0 = reinterpret_cast<const float*>(&xv[0]);
    const float* xf1 = reinterpret_cast<const float*>(&xv[1]);
#pragma unroll
    for (int kk = 0; kk < 4; ++kk) {
      float w[MC];
#pragma unroll
      for (int j = 0; j < MC; ++j) w[j] = Ws[(k4 + kk) * M + c * MC + j];
      float x0 = xf0[kk], x1 = xf1[kk];
#pragma unroll
      for (int j = 0; j < MC; ++j) {
        acc[0][j] += x0 * w[j];
        acc[1][j] += x1 * w[j];
      }
    }
  }
#pragma unroll
  for (int rr = 0; rr < 2; ++rr) {
    int gr = row0 + rt + 16 * rr;
    if (gr < n) {
#pragma unroll
      for (int j = 0; j < MC; ++j)
        Y[(size_t)gr * M + c * MC + j] = __float2half(acc[rr][j]);
    }
  }
}

// ---------------------------------------------------------------------------
// Fused GCN layer: out_row = relu(agg(h) + bias); y = out_row @ W (fp16).
// Block = 32 nodes; 8 lanes/node own 8 features each (16B gathers).
// ---------------------------------------------------------------------------
__device__ inline void h8_acc(uint4 r, float w, float* acc) {
  const __half2* hp = reinterpret_cast<const __half2*>(&r);
#pragma unroll
  for (int q = 0; q < 4; ++q) {
    float2 f = __half22float2(hp[q]);
    acc[2 * q]     += w * f.x;
    acc[2 * q + 1] += w * f.y;
  }
}

template <int FOUT>
__global__ __launch_bounds__(256) void agg_gemm_kernel(
    const __half* __restrict__ h, const int* __restrict__ offs,
    const int* __restrict__ csr, const float* __restrict__ dinv,
    const float* __restrict__ bias, const float* __restrict__ W,
    __half* __restrict__ y, int n) {
  constexpr int FIN = 64;
  constexpr int XST = FIN + 4;
  __shared__ float Xs[32 * XST];
  __shared__ __align__(16) float Wls[FIN * FOUT];
  const int t = threadIdx.x;
  for (int i = t * 4; i < FIN * FOUT; i += 1024)
    *reinterpret_cast<float4*>(&Wls[i]) = *reinterpret_cast<const float4*>(&W[i]);
  const int r = t >> 3;            // local node 0..31
  const int node = blockIdx.x * 32 + r;
  const int fl = (t & 7) * 8;
  float acc[8];
#pragma unroll
  for (int j = 0; j < 8; ++j) acc[j] = 0.f;
  if (node < n) {
    const int e0 = offs[node], e1 = offs[node + 1];
    const float di = dinv[node];
    {
      uint4 rr = *reinterpret_cast<const uint4*>(h + (size_t)node * FIN + fl);
      h8_acc(rr, di * di, acc);
    }
    int e = e0;
    for (; e + 4 <= e1; e += 4) {
      int sidx[4];
      float wv[4];
      uint4 rv[4];
#pragma unroll
      for (int u = 0; u < 4; ++u) sidx[u] = csr[e + u];
#pragma unroll
      for (int u = 0; u < 4; ++u) wv[u] = di * dinv[sidx[u]];
#pragma unroll
      for (int u = 0; u < 4; ++u)
        rv[u] = *reinterpret_cast<const uint4*>(h + (size_t)sidx[u] * FIN + fl);
#pragma unroll
      for (int u = 0; u < 4; ++u) h8_acc(rv[u], wv[u], acc);
    }
    for (; e < e1; ++e) {
      int s = csr[e];
      uint4 rr = *reinterpret_cast<const uint4*>(h + (size_t)s * FIN + fl);
      h8_acc(rr, di * dinv[s], acc);
    }
#pragma unroll
    for (int j = 0; j < 8; ++j)
      Xs[r * XST + fl + j] = fmaxf(acc[j] + bias[fl + j], 0.f);
  }
  __syncthreads();
  // GEMM: thread computes its node's cols c0..c0+CPT-1
  constexpr int CPT = FOUT / 8;
  const int c0 = (t & 7) * CPT;
  float a2[CPT];
#pragma unroll
  for (int j = 0; j < CPT; ++j) a2[j] = 0.f;
  for (int k = 0; k < FIN; ++k) {
    float xv = Xs[r * XST + k];
    const float4 wa = *reinterpret_cast<const float4*>(&Wls[k * FOUT + c0]);
    a2[0] += xv * wa.x; a2[1] += xv * wa.y;
    a2[2] += xv * wa.z; a2[3] += xv * wa.w;
    if constexpr (CPT == 8) {
      const float4 wb = *reinterpret_cast<const float4*>(&Wls[k * FOUT + c0 + 4]);
      a2[4] += xv * wb.x; a2[5] += xv * wb.y;
      a2[6] += xv * wb.z; a2[7] += xv * wb.w;
    }
  }
  if (node < n) {
    union { __half hh[CPT]; uint4 u4; uint2 u2; } cv;
#pragma unroll
    for (int j = 0; j < CPT; ++j) cv.hh[j] = __float2half(a2[j]);
    if constexpr (CPT == 8)
      *reinterpret_cast<uint4*>(y + (size_t)node * FOUT + c0) = cv.u4;
    else
      *reinterpret_cast<uint2*>(y + (size_t)node * FOUT + c0) = cv.u2;
  }
}

// ---------------------------------------------------------------------------
// Layer 3 aggregate (F=32) + relu/bias + hierarchical pool: LDS per-graph
// window (batch sorted -> a 64-node block spans ~1-3 graphs), one flush.
// ---------------------------------------------------------------------------
__global__ __launch_bounds__(256) void agg_pool_kernel(const __half* __restrict__ h,
    const int* __restrict__ offs, const int* __restrict__ csr,
    const float* __restrict__ dinv, const float* __restrict__ bias,
    const int* __restrict__ batch, float* __restrict__ gsum, int n, int G) {
  constexpr int F = 32;
  constexpr int GCAP = 8;
  __shared__ float lg[GCAP * F];
  const int t = threadIdx.x;
  const int node0 = blockIdx.x * 64;
  const int node = node0 + (t >> 2);
  const int fl = (t & 3) * 8;
  for (int i = t; i < GCAP * F; i += 256) lg[i] = 0.f;
  __syncthreads();
  const int g0 = batch[node0 < n ? node0 : (n - 1)];
  if (node < n) {
    const int e0 = offs[node], e1 = offs[node + 1];
    const float di = dinv[node];
    float acc[8];
#pragma unroll
    for (int j = 0; j < 8; ++j) acc[j] = 0.f;
    {
      uint4 rr = *reinterpret_cast<const uint4*>(h + (size_t)node * F + fl);
      h8_acc(rr, di * di, acc);
    }
    int e = e0;
    for (; e + 4 <= e1; e += 4) {
      int sidx[4];
      float wv[4];
      uint4 rv[4];
#pragma unroll
      for (int u = 0; u < 4; ++u) sidx[u] = csr[e + u];
#pragma unroll
      for (int u = 0; u < 4; ++u) wv[u] = di * dinv[sidx[u]];
#pragma unroll
      for (int u = 0; u < 4; ++u)
        rv[u] = *reinterpret_cast<const uint4*>(h + (size_t)sidx[u] * F + fl);
#pragma unroll
      for (int u = 0; u < 4; ++u) h8_acc(rv[u], wv[u], acc);
    }
    for (; e < e1; ++e) {
      int s = csr[e];
      uint4 rr = *reinterpret_cast<const uint4*>(h + (size_t)s * F + fl);
      h8_acc(rr, di * dinv[s], acc);
    }
    const int rel = batch[node] - g0;
    if (rel < GCAP) {
#pragma unroll
      for (int j = 0; j < 8; ++j)
        atomicAdd(&lg[rel * F + fl + j], fmaxf(acc[j] + bias[fl + j], 0.f));
    } else {  // pathological span: direct (rare)
      float* gp = gsum + (size_t)batch[node] * F + fl;
#pragma unroll
      for (int j = 0; j < 8; ++j)
        atomicAdd(&gp[j], fmaxf(acc[j] + bias[fl + j], 0.f));
    }
  }
  __syncthreads();
  for (int i = t; i < GCAP * F; i += 256) {
    float v = lg[i];
    int gi = g0 * F + i;
    if (v != 0.f && gi < G * F) atomicAdd(&gsum[gi], v);
  }
}

// One thread per graph: range via binary search, mean, MLP, log_softmax.
__global__ __launch_bounds__(256) void head_kernel(const float* __restrict__ gsum,
    const int* __restrict__ batch, const float* __restrict__ Wc1,
    const float* __restrict__ bc1, const float* __restrict__ Wc2,
    const float* __restrict__ bc2, float* __restrict__ out, int n, int G) {
  int g = blockIdx.x * blockDim.x + threadIdx.x;
  if (g >= G) return;
  int lo = 0, hi = n;
  while (lo < hi) { int m = (lo + hi) >> 1; if (batch[m] < g) lo = m + 1; else hi = m; }
  const int s0 = lo;
  lo = s0; hi = n;
  while (lo < hi) { int m = (lo + hi) >> 1; if (batch[m] < g + 1) lo = m + 1; else hi = m; }
  const float inv = 1.0f / fmaxf((float)(lo - s0), 1.0f);
  float p[32];
#pragma unroll
  for (int k = 0; k < 32; ++k) p[k] = gsum[g * 32 + k] * inv;
  float z[16];
#pragma unroll
  for (int j = 0; j < 16; ++j) {
    float a = bc1[j];
#pragma unroll
    for (int k = 0; k < 32; ++k) a += p[k] * Wc1[k * 16 + j];
    z[j] = fmaxf(a, 0.f);
  }
  float lg[16];
  float m = -1e30f;
#pragma unroll
  for (int j = 0; j < 16; ++j) {
    float a = bc2[j];
#pragma unroll
    for (int k = 0; k < 16; ++k) a += z[k] * Wc2[k * 16 + j];
    lg[j] = a;
    m = fmaxf(m, a);
  }
  float ssum = 0.f;
#pragma unroll
  for (int j = 0; j < 16; ++j) ssum += expf(lg[j] - m);
  float lse = logf(ssum);
#pragma unroll
  for (int j = 0; j < 16; ++j) out[g * 16 + j] = lg[j] - m - lse;
}

extern "C" void kernel_launch(void* const* d_in, const int* in_sizes, int n_in,
                              void* d_out, int out_size, void* d_ws, size_t ws_size,
                              hipStream_t stream) {
  const float* x   = (const float*)d_in[0];
  const int*   ei  = (const int*)d_in[1];
  const int*   batch = (const int*)d_in[2];
  const float* W1 = (const float*)d_in[3];
  const float* b1 = (const float*)d_in[4];
  const float* W2 = (const float*)d_in[5];
  const float* b2 = (const float*)d_in[6];
  const float* W3 = (const float*)d_in[7];
  const float* b3 = (const float*)d_in[8];
  const float* Wc1 = (const float*)d_in[9];
  const float* bc1 = (const float*)d_in[10];
  const float* Wc2 = (const float*)d_in[11];
  const float* bc2 = (const float*)d_in[12];

  const int N = in_sizes[2];        // 100000
  const int E = in_sizes[1] / 2;    // 3200000
  const int G = out_size / 16;      // 1024
  const int* src = ei;
  const int* dst = ei + E;
  const int nbuckets = (N + ((1 << BSHIFT) - 1)) >> BSHIFT;  // 391
  const int nblk = (E + EPB - 1) / EPB;                      // 782

  char* ws = (char*)d_ws;
  size_t off = 0;
  auto alloc = [&](size_t bytes) -> void* {
    void* p = ws + off;
    off += (bytes + 511) & ~(size_t)511;
    return p;
  };
  int*   offs   = (int*)alloc(((size_t)N + 1) * 4);
  float* dinv   = (float*)alloc((size_t)N * 4);
  int*   bucket_cnt  = (int*)alloc(2048);
  int*   bucket_base = (int*)alloc(2048);
  unsigned* runmap = (unsigned*)alloc((size_t)nbuckets * nblk * 4);  // 1.2MB
  int*   csr    = (int*)alloc((size_t)E * 4);
  __half* hbufA = (__half*)alloc((size_t)N * 64 * 2);   // layer1 gemm out
  __half* hbufB = (__half*)alloc((size_t)N * 64 * 2);   // layer2 fused out
  __half* hbufC = (__half*)alloc((size_t)N * 32 * 2);   // layer3 fused out
  float* gsum   = (float*)alloc((size_t)G * 32 * 4);    // pooled sums
  // partition segments (E*4 = 12.8MB) alias hbufA (12.8MB): consumed by
  // fill_bucket before gemm1 writes hbufA.
  unsigned* part = (unsigned*)hbufA;
  (void)ws_size; (void)n_in;

  // --- CSR build (reused by all 3 layers) ---
  hipMemsetAsync(bucket_cnt, 0, (size_t)nbuckets * 4, stream);
  hipMemsetAsync(gsum, 0, (size_t)G * 32 * 4, stream);
  partition_kernel<<<nblk, 512, 0, stream>>>(src, dst, bucket_cnt, part, runmap,
                                             E, nbuckets, nblk);
  scan_buckets_kernel<<<1, 256, 0, stream>>>(bucket_cnt, bucket_base, nbuckets);
  fill_bucket_kernel<<<nbuckets, 512, 0, stream>>>(part, runmap, bucket_cnt,
                                                   bucket_base, offs, dinv, csr,
                                                   N, E, nblk);

  // --- layer 1 GEMM: x[N,128] @ W1 -> hbufA fp16 ---
  gemm_kernel<128, 64><<<(N + 31) / 32, 256, 0, stream>>>(x, W1, hbufA, N);
  // --- fused layer1-agg + layer2-GEMM: hbufA -> hbufB ---
  agg_gemm_kernel<64><<<(N + 31) / 32, 256, 0, stream>>>(hbufA, offs, csr, dinv,
                                                         b1, W2, hbufB, N);
  // --- fused layer2-agg + layer3-GEMM: hbufB -> hbufC ---
  agg_gemm_kernel<32><<<(N + 31) / 32, 256, 0, stream>>>(hbufB, offs, csr, dinv,
                                                         b2, W3, hbufC, N);
  // --- layer3-agg + hierarchical pool ---
  agg_pool_kernel<<<(N + 63) / 64, 256, 0, stream>>>(hbufC, offs, csr, dinv,
                                                     b3, batch, gsum, N, G);
  // --- head: mean + MLP + log_softmax ---
  head_kernel<<<(G + 255) / 256, 256, 0, stream>>>(gsum, batch, Wc1, bc1,
                                                   Wc2, bc2, (float*)d_out, N, G);
}